// Round 8
// baseline (349.245 us; speedup 1.0000x reference)
//
#include <hip/hip_runtime.h>
#include <hip/hip_bf16.h>

// y = (softmax((xWq)(xWk)^T/8) + B) @ (xWv); b=2 s=2048 d=1024 h=16 hd=64
// conv_x -> wtrans -> qkv_gemm (m97-style, V written pre-transposed) -> attn
// R8 = R7 EXACTLY, but attn_kernel is launched TWICE (idempotent, deterministic)
// as a timing probe: T_attn = dur(R8) - dur(R7). No other changes.

typedef __attribute__((ext_vector_type(4))) float  f32x4;
typedef __attribute__((ext_vector_type(8))) short  bf16x8;
typedef __attribute__((ext_vector_type(4))) short  s16x4;
typedef __attribute__((ext_vector_type(4))) unsigned u32x4;

__device__ __forceinline__ short f2bf(float f) {
    __hip_bfloat16 h = __float2bfloat16(f);
    return __builtin_bit_cast(short, h);
}

__device__ __forceinline__ unsigned cvt_pk_bf16(float lo, float hi) {
    unsigned w;
    asm("v_cvt_pk_bf16_f32 %0, %1, %2" : "=v"(w) : "v"(lo), "v"(hi));
    return w;
}

__device__ __forceinline__ bf16x8 pack8(f32x4 a, f32x4 b) {
    u32x4 t = (u32x4){cvt_pk_bf16(a[0], a[1]), cvt_pk_bf16(a[2], a[3]),
                      cvt_pk_bf16(b[0], b[1]), cvt_pk_bf16(b[2], b[3])};
    return __builtin_bit_cast(bf16x8, t);
}

__device__ __forceinline__ void gll16(const short* g, short* l) {
    __builtin_amdgcn_global_load_lds(
        (const __attribute__((address_space(1))) void*)g,
        (__attribute__((address_space(3))) void*)l, 16, 0, 0);
}

// ---------------- conv_x ----------------
__global__ void conv_x_kernel(const float* __restrict__ x, short* __restrict__ xb) {
    int idx = blockIdx.x * 256 + threadIdx.x;
    f32x4 v = *reinterpret_cast<const f32x4*>(x + (size_t)idx * 4);
    s16x4 o;
    o[0] = f2bf(v[0]); o[1] = f2bf(v[1]); o[2] = f2bf(v[2]); o[3] = f2bf(v[3]);
    *reinterpret_cast<s16x4*>(xb + (size_t)idx * 4) = o;
}

// ---------------- wtrans ----------------
__global__ void wtrans_kernel(const float* __restrict__ W, short* __restrict__ Wt) {
    __shared__ float tile[64][65];
    int kb = blockIdx.x, nb = blockIdx.y;
    int t = threadIdx.x;
    int c4 = (t & 15) * 4;
    int r0 = t >> 4;
#pragma unroll
    for (int rr = 0; rr < 4; ++rr) {
        int kl = r0 + rr * 16;
        f32x4 v = *reinterpret_cast<const f32x4*>(W + (size_t)(kb * 64 + kl) * 3072 + nb * 64 + c4);
        tile[kl][c4 + 0] = v[0]; tile[kl][c4 + 1] = v[1];
        tile[kl][c4 + 2] = v[2]; tile[kl][c4 + 3] = v[3];
    }
    __syncthreads();
#pragma unroll
    for (int rr = 0; rr < 4; ++rr) {
        int nl = r0 + rr * 16;
        s16x4 o;
#pragma unroll
        for (int i = 0; i < 4; ++i) o[i] = f2bf(tile[c4 + i][nl]);
        *reinterpret_cast<s16x4*>(Wt + (size_t)(nb * 64 + nl) * 1024 + kb * 64 + c4) = o;
    }
}

// ---------------- qkv_gemm (m97 structure; V written transposed) ----------------
__global__ __launch_bounds__(256) void qkv_gemm_kernel(
    const short* __restrict__ xb, const short* __restrict__ Wt,
    const float* __restrict__ bias,
    short* __restrict__ Qo, short* __restrict__ Ko, short* __restrict__ Vto)
{
    __shared__ short As[128 * 64];
    __shared__ short Bs[128 * 64];
    int tid = threadIdx.x;
    int wave = tid >> 6, lane = tid & 63, g = lane >> 4, lr = lane & 15;
    int wr = wave >> 1, wc = wave & 1;
    int bm = blockIdx.x, bn = blockIdx.y;

    f32x4 acc[4][4];
#pragma unroll
    for (int a = 0; a < 4; ++a)
#pragma unroll
        for (int b = 0; b < 4; ++b) acc[a][b] = (f32x4){0.f, 0.f, 0.f, 0.f};

    for (int k0 = 0; k0 < 1024; k0 += 64) {
#pragma unroll
        for (int j = 0; j < 4; ++j) {
            int c = j * 256 + tid;
            int row = c >> 3, cc = c & 7;
            int scc = (cc ^ (row & 7)) * 8;
            gll16(xb + (size_t)(bm * 128 + row) * 1024 + k0 + scc,
                  &As[(j * 256 + wave * 64) * 8]);
            gll16(Wt + (size_t)(bn * 128 + row) * 1024 + k0 + scc,
                  &Bs[(j * 256 + wave * 64) * 8]);
        }
        __syncthreads();

        bf16x8 af[2][4], bfr[2][4];
#pragma unroll
        for (int mt = 0; mt < 4; ++mt) {
            int row = wr * 64 + mt * 16 + lr;
            af[0][mt] = *reinterpret_cast<const bf16x8*>(&As[row * 64 + (((g    ) ^ (lr & 7)) * 8)]);
            af[1][mt] = *reinterpret_cast<const bf16x8*>(&As[row * 64 + (((g + 4) ^ (lr & 7)) * 8)]);
        }
#pragma unroll
        for (int nt = 0; nt < 4; ++nt) {
            int row = wc * 64 + nt * 16 + lr;
            bfr[0][nt] = *reinterpret_cast<const bf16x8*>(&Bs[row * 64 + (((g    ) ^ (lr & 7)) * 8)]);
            bfr[1][nt] = *reinterpret_cast<const bf16x8*>(&Bs[row * 64 + (((g + 4) ^ (lr & 7)) * 8)]);
        }
#pragma unroll
        for (int mt = 0; mt < 4; ++mt)
#pragma unroll
            for (int nt = 0; nt < 4; ++nt) {
                acc[mt][nt] = __builtin_amdgcn_mfma_f32_16x16x32_bf16(af[0][mt], bfr[0][nt], acc[mt][nt], 0, 0, 0);
                acc[mt][nt] = __builtin_amdgcn_mfma_f32_16x16x32_bf16(af[1][mt], bfr[1][nt], acc[mt][nt], 0, 0, 0);
            }
        __syncthreads();
    }

#pragma unroll
    for (int nt = 0; nt < 4; ++nt) {
        int n = bn * 128 + wc * 64 + nt * 16 + lr;
        float bv = bias[n];
        int which = n >> 10;
        int h = (n >> 6) & 15;
        int dd = n & 63;
#pragma unroll
        for (int mt = 0; mt < 4; ++mt) {
            int m0 = bm * 128 + wr * 64 + mt * 16 + g * 4;
            int bb = m0 >> 11, s0 = m0 & 2047;
            if (which == 2) {
                s16x4 o;
#pragma unroll
                for (int r = 0; r < 4; ++r) o[r] = f2bf(acc[mt][nt][r] + bv);
                *reinterpret_cast<s16x4*>(
                    Vto + ((size_t)(bb * 16 + h) * 64 + dd) * 2048 + s0) = o;
            } else {
                short* base = (which == 0) ? Qo : Ko;
#pragma unroll
                for (int r = 0; r < 4; ++r)
                    base[(((size_t)bb * 16 + h) * 2048 + s0 + r) * 64 + dd] =
                        f2bf(acc[mt][nt][r] + bv);
            }
        }
    }
}

// ---------------- attn ----------------
__global__ __launch_bounds__(512, 4) void attn_kernel(
    const short* __restrict__ Qw, const short* __restrict__ Kw, const short* __restrict__ Vtw,
    const float* __restrict__ attnB, float* __restrict__ out)
{
    __shared__ short Ks [2][64 * 64];
    __shared__ short Vts[2][64 * 64];
    __shared__ short Ps [8][16 * 64];

    int id = blockIdx.x;
    int bh3 = id & 7;
    int qt  = (id >> 3) & 15;
    int bh  = ((id >> 7) << 3) | bh3;
    int b = bh >> 4, h = bh & 15;
    int tid = threadIdx.x;
    int wave = tid >> 6, lane = tid & 63, g = lane >> 4, lr = lane & 15;

    const short* Qb = Qw  + (size_t)bh * 2048 * 64;
    const short* Kb = Kw  + (size_t)bh * 2048 * 64;
    const short* Vb = Vtw + (size_t)bh * 64 * 2048;
    const float* Bp = attnB + (size_t)bh * 2048 * 2048;

    int qbase = qt * 128 + wave * 16;

    bf16x8 qf0, qf1;
    {
        const short* qp = Qb + (size_t)(qbase + lr) * 64 + g * 8;
        qf0 = *reinterpret_cast<const bf16x8*>(qp);
        qf1 = *reinterpret_cast<const bf16x8*>(qp + 32);
    }
    const float* brow = Bp + (size_t)(qbase + lr) * 2048 + g * 8;

    f32x4 Os[4], Ob[4];
#pragma unroll
    for (int dt = 0; dt < 4; ++dt) { Os[dt] = (f32x4){0.f,0.f,0.f,0.f}; Ob[dt] = (f32x4){0.f,0.f,0.f,0.f}; }
    float lsum = 0.f;

#define STAGE_KV(buf, ktt) do {                                                   \
    int row = tid >> 3, cc = tid & 7;                                             \
    int scc = (cc ^ (row & 7)) * 8;                                               \
    gll16(Kb + (size_t)((ktt) * 64 + row) * 64 + scc,                             \
          &Ks[buf][wave * 512]);                                                  \
    gll16(Vb + (size_t)row * 2048 + (ktt) * 64 + scc,                             \
          &Vts[buf][wave * 512]);                                                 \
} while (0)

#define LOADB(d0, d1, d2, d3, ktt) do {                                           \
    const float* bp_ = brow + (size_t)(ktt) * 64;                                 \
    d0 = *reinterpret_cast<const f32x4*>(bp_);                                    \
    d1 = *reinterpret_cast<const f32x4*>(bp_ + 4);                                \
    d2 = *reinterpret_cast<const f32x4*>(bp_ + 32);                               \
    d3 = *reinterpret_cast<const f32x4*>(bp_ + 36);                               \
} while (0)

#define COMPUTE(cur, xb0, xb1) do {                                               \
    f32x4 S[4];                                                                   \
    __builtin_amdgcn_s_setprio(1);                                                \
    _Pragma("unroll")                                                             \
    for (int nt = 0; nt < 4; ++nt) {                                              \
        int row = nt * 16 + lr;                                                   \
        bf16x8 kf0 = *reinterpret_cast<const bf16x8*>(&Ks[cur][row * 64 + (((g    ) ^ (lr & 7)) * 8)]); \
        bf16x8 kf1 = *reinterpret_cast<const bf16x8*>(&Ks[cur][row * 64 + (((g + 4) ^ (lr & 7)) * 8)]); \
        f32x4 s = (f32x4){0.f,0.f,0.f,0.f};                                       \
        s = __builtin_amdgcn_mfma_f32_16x16x32_bf16(kf0, qf0, s, 0, 0, 0);        \
        s = __builtin_amdgcn_mfma_f32_16x16x32_bf16(kf1, qf1, s, 0, 0, 0);        \
        S[nt] = s;                                                                \
    }                                                                             \
    __builtin_amdgcn_s_setprio(0);                                                \
    _Pragma("unroll")                                                             \
    for (int nt = 0; nt < 4; ++nt)                                                \
        _Pragma("unroll")                                                         \
        for (int r = 0; r < 4; ++r) {                                             \
            float p = exp2f(S[nt][r] * 0.1803368801111f);                         \
            S[nt][r] = p;                                                         \
            lsum += p;                                                            \
        }                                                                         \
    short* psw = &Ps[wave][lr * 64];                                              \
    _Pragma("unroll")                                                             \
    for (int nt = 0; nt < 4; ++nt)                                                \
        _Pragma("unroll")                                                         \
        for (int rp = 0; rp < 2; ++rp) {                                          \
            unsigned w = cvt_pk_bf16(S[nt][2 * rp], S[nt][2 * rp + 1]);           \
            int kp = 8 * nt + 2 * g + rp;                                         \
            int bi = kp >> 2, off = kp & 3;                                       \
            *reinterpret_cast<unsigned*>(psw + ((bi ^ (lr & 7)) << 3) + off * 2) = w; \
        }                                                                         \
    bf16x8 pf0 = *reinterpret_cast<const bf16x8*>(&Ps[wave][lr * 64 + (((g    ) ^ (lr & 7)) * 8)]); \
    bf16x8 pf1 = *reinterpret_cast<const bf16x8*>(&Ps[wave][lr * 64 + (((g + 4) ^ (lr & 7)) * 8)]); \
    __builtin_amdgcn_s_setprio(1);                                                \
    _Pragma("unroll")                                                             \
    for (int dt = 0; dt < 4; ++dt) {                                              \
        int row = dt * 16 + lr;                                                   \
        bf16x8 v0 = *reinterpret_cast<const bf16x8*>(&Vts[cur][row * 64 + (((g    ) ^ (lr & 7)) * 8)]); \
        bf16x8 v1 = *reinterpret_cast<const bf16x8*>(&Vts[cur][row * 64 + (((g + 4) ^ (lr & 7)) * 8)]); \
        Os[dt] = __builtin_amdgcn_mfma_f32_16x16x32_bf16(pf0, v0, Os[dt], 0, 0, 0); \
        Os[dt] = __builtin_amdgcn_mfma_f32_16x16x32_bf16(pf1, v1, Os[dt], 0, 0, 0); \
        Ob[dt] = __builtin_amdgcn_mfma_f32_16x16x32_bf16(xb0, v0, Ob[dt], 0, 0, 0); \
        Ob[dt] = __builtin_amdgcn_mfma_f32_16x16x32_bf16(xb1, v1, Ob[dt], 0, 0, 0); \
    }                                                                             \
    __builtin_amdgcn_s_setprio(0);                                                \
} while (0)

    f32x4 a0, a1, a2, a3, p0, p1, p2, p3;

    STAGE_KV(0, 0);
    __builtin_amdgcn_sched_barrier(0);
    LOADB(a0, a1, a2, a3, 0);
    LOADB(p0, p1, p2, p3, 1);
    __builtin_amdgcn_sched_barrier(0);
    asm volatile("s_waitcnt vmcnt(8)" ::: "memory");
    __builtin_amdgcn_s_barrier();
    __builtin_amdgcn_sched_barrier(0);

    for (int t = 0; t < 16; ++t) {
        {
            bf16x8 bbf0 = pack8(a0, a1);
            bf16x8 bbf1 = pack8(a2, a3);
            STAGE_KV(1, 2 * t + 1);
            __builtin_amdgcn_sched_barrier(0);
            if (t < 15) LOADB(a0, a1, a2, a3, 2 * t + 2);
            __builtin_amdgcn_sched_barrier(0);
            COMPUTE(0, bbf0, bbf1);
            if (t < 15) {
                asm volatile("s_waitcnt vmcnt(4)" ::: "memory");
            } else {
                asm volatile("s_waitcnt vmcnt(0)" ::: "memory");
            }
            __builtin_amdgcn_s_barrier();
            __builtin_amdgcn_sched_barrier(0);
        }
        {
            bf16x8 bbf0 = pack8(p0, p1);
            bf16x8 bbf1 = pack8(p2, p3);
            if (t < 15) {
                STAGE_KV(0, 2 * t + 2);
                __builtin_amdgcn_sched_barrier(0);
                LOADB(p0, p1, p2, p3, 2 * t + 3);
                __builtin_amdgcn_sched_barrier(0);
            }
            COMPUTE(1, bbf0, bbf1);
            if (t < 15) {
                asm volatile("s_waitcnt vmcnt(4)" ::: "memory");
                __builtin_amdgcn_s_barrier();
                __builtin_amdgcn_sched_barrier(0);
            }
        }
    }
#undef STAGE_KV
#undef LOADB
#undef COMPUTE

    float l = lsum;
    l += __shfl_xor(l, 16);
    l += __shfl_xor(l, 32);
    float inv = 1.0f / l;
#pragma unroll
    for (int r = 0; r < 4; ++r) {
        float invr = __shfl(inv, g * 4 + r);
        int q = qbase + g * 4 + r;
#pragma unroll
        for (int dt = 0; dt < 4; ++dt) {
            int dcol = dt * 16 + lr;
            float v = Os[dt][r] * invr + Ob[dt][r];
            __builtin_nontemporal_store(v, &out[((size_t)(b * 2048 + q) * 16 + h) * 64 + dcol]);
        }
    }
}

extern "C" void kernel_launch(void* const* d_in, const int* in_sizes, int n_in,
                              void* d_out, int out_size, void* d_ws, size_t ws_size,
                              hipStream_t stream) {
    const float* x     = (const float*)d_in[0];
    const float* attnB = (const float*)d_in[1];
    const float* W     = (const float*)d_in[2];
    const float* bias  = (const float*)d_in[3];
    float* out = (float*)d_out;

    short* ws = (short*)d_ws;
    short* xb = ws;                // 4,194,304 shorts
    short* Wt = xb + 4194304;      // 3,145,728
    short* Q  = Wt + 3145728;      // 4,194,304
    short* K  = Q  + 4194304;      // 4,194,304
    short* Vt = K  + 4194304;      // 4,194,304

    conv_x_kernel<<<4096, 256, 0, stream>>>(x, xb);
    wtrans_kernel<<<dim3(16, 48), 256, 0, stream>>>(W, Wt);
    qkv_gemm_kernel<<<dim3(32, 24), 256, 0, stream>>>(xb, Wt, bias, Q, K, Vt);
    // TIMING PROBE: attn launched twice (idempotent; identical output).
    // T_attn = dur(this round) - dur(R7).
    attn_kernel<<<512, 512, 0, stream>>>(Q, K, Vt, attnB, out);
    attn_kernel<<<512, 512, 0, stream>>>(Q, K, Vt, attnB, out);
}

// Round 9
// 215.949 us; speedup vs baseline: 1.6173x; 1.6173x over previous
//
#include <hip/hip_runtime.h>
#include <hip/hip_bf16.h>

// y = (softmax((xWq)(xWk)^T/8) + B) @ (xWv); b=2 s=2048 d=1024 h=16 hd=64
// conv_x -> wtrans -> qkv_gemm (m97-style, V written pre-transposed) -> attn
// attn R9: 4-buffer K/V ring staged 3 tiles ahead (stage cover ~3 iters),
//   FIFO-counted vmcnt(6) steady state, exact tail counts; bias 2-deep
//   prefetch unchanged. LDS 80KB (ring 64 + Ps 16), 2 blocks/CU (grid-pinned).

typedef __attribute__((ext_vector_type(4))) float  f32x4;
typedef __attribute__((ext_vector_type(8))) short  bf16x8;
typedef __attribute__((ext_vector_type(4))) short  s16x4;
typedef __attribute__((ext_vector_type(4))) unsigned u32x4;

__device__ __forceinline__ short f2bf(float f) {
    __hip_bfloat16 h = __float2bfloat16(f);
    return __builtin_bit_cast(short, h);
}

__device__ __forceinline__ unsigned cvt_pk_bf16(float lo, float hi) {
    unsigned w;
    asm("v_cvt_pk_bf16_f32 %0, %1, %2" : "=v"(w) : "v"(lo), "v"(hi));
    return w;
}

__device__ __forceinline__ bf16x8 pack8(f32x4 a, f32x4 b) {
    u32x4 t = (u32x4){cvt_pk_bf16(a[0], a[1]), cvt_pk_bf16(a[2], a[3]),
                      cvt_pk_bf16(b[0], b[1]), cvt_pk_bf16(b[2], b[3])};
    return __builtin_bit_cast(bf16x8, t);
}

__device__ __forceinline__ void gll16(const short* g, short* l) {
    __builtin_amdgcn_global_load_lds(
        (const __attribute__((address_space(1))) void*)g,
        (__attribute__((address_space(3))) void*)l, 16, 0, 0);
}

// ---------------- conv_x ----------------
__global__ void conv_x_kernel(const float* __restrict__ x, short* __restrict__ xb) {
    int idx = blockIdx.x * 256 + threadIdx.x;
    f32x4 v = *reinterpret_cast<const f32x4*>(x + (size_t)idx * 4);
    s16x4 o;
    o[0] = f2bf(v[0]); o[1] = f2bf(v[1]); o[2] = f2bf(v[2]); o[3] = f2bf(v[3]);
    *reinterpret_cast<s16x4*>(xb + (size_t)idx * 4) = o;
}

// ---------------- wtrans ----------------
__global__ void wtrans_kernel(const float* __restrict__ W, short* __restrict__ Wt) {
    __shared__ float tile[64][65];
    int kb = blockIdx.x, nb = blockIdx.y;
    int t = threadIdx.x;
    int c4 = (t & 15) * 4;
    int r0 = t >> 4;
#pragma unroll
    for (int rr = 0; rr < 4; ++rr) {
        int kl = r0 + rr * 16;
        f32x4 v = *reinterpret_cast<const f32x4*>(W + (size_t)(kb * 64 + kl) * 3072 + nb * 64 + c4);
        tile[kl][c4 + 0] = v[0]; tile[kl][c4 + 1] = v[1];
        tile[kl][c4 + 2] = v[2]; tile[kl][c4 + 3] = v[3];
    }
    __syncthreads();
#pragma unroll
    for (int rr = 0; rr < 4; ++rr) {
        int nl = r0 + rr * 16;
        s16x4 o;
#pragma unroll
        for (int i = 0; i < 4; ++i) o[i] = f2bf(tile[c4 + i][nl]);
        *reinterpret_cast<s16x4*>(Wt + (size_t)(nb * 64 + nl) * 1024 + kb * 64 + c4) = o;
    }
}

// ---------------- qkv_gemm (m97 structure; V written transposed) ----------------
__global__ __launch_bounds__(256) void qkv_gemm_kernel(
    const short* __restrict__ xb, const short* __restrict__ Wt,
    const float* __restrict__ bias,
    short* __restrict__ Qo, short* __restrict__ Ko, short* __restrict__ Vto)
{
    __shared__ short As[128 * 64];
    __shared__ short Bs[128 * 64];
    int tid = threadIdx.x;
    int wave = tid >> 6, lane = tid & 63, g = lane >> 4, lr = lane & 15;
    int wr = wave >> 1, wc = wave & 1;
    int bm = blockIdx.x, bn = blockIdx.y;

    f32x4 acc[4][4];
#pragma unroll
    for (int a = 0; a < 4; ++a)
#pragma unroll
        for (int b = 0; b < 4; ++b) acc[a][b] = (f32x4){0.f, 0.f, 0.f, 0.f};

    for (int k0 = 0; k0 < 1024; k0 += 64) {
#pragma unroll
        for (int j = 0; j < 4; ++j) {
            int c = j * 256 + tid;
            int row = c >> 3, cc = c & 7;
            int scc = (cc ^ (row & 7)) * 8;
            gll16(xb + (size_t)(bm * 128 + row) * 1024 + k0 + scc,
                  &As[(j * 256 + wave * 64) * 8]);
            gll16(Wt + (size_t)(bn * 128 + row) * 1024 + k0 + scc,
                  &Bs[(j * 256 + wave * 64) * 8]);
        }
        __syncthreads();

        bf16x8 af[2][4], bfr[2][4];
#pragma unroll
        for (int mt = 0; mt < 4; ++mt) {
            int row = wr * 64 + mt * 16 + lr;
            af[0][mt] = *reinterpret_cast<const bf16x8*>(&As[row * 64 + (((g    ) ^ (lr & 7)) * 8)]);
            af[1][mt] = *reinterpret_cast<const bf16x8*>(&As[row * 64 + (((g + 4) ^ (lr & 7)) * 8)]);
        }
#pragma unroll
        for (int nt = 0; nt < 4; ++nt) {
            int row = wc * 64 + nt * 16 + lr;
            bfr[0][nt] = *reinterpret_cast<const bf16x8*>(&Bs[row * 64 + (((g    ) ^ (lr & 7)) * 8)]);
            bfr[1][nt] = *reinterpret_cast<const bf16x8*>(&Bs[row * 64 + (((g + 4) ^ (lr & 7)) * 8)]);
        }
#pragma unroll
        for (int mt = 0; mt < 4; ++mt)
#pragma unroll
            for (int nt = 0; nt < 4; ++nt) {
                acc[mt][nt] = __builtin_amdgcn_mfma_f32_16x16x32_bf16(af[0][mt], bfr[0][nt], acc[mt][nt], 0, 0, 0);
                acc[mt][nt] = __builtin_amdgcn_mfma_f32_16x16x32_bf16(af[1][mt], bfr[1][nt], acc[mt][nt], 0, 0, 0);
            }
        __syncthreads();
    }

#pragma unroll
    for (int nt = 0; nt < 4; ++nt) {
        int n = bn * 128 + wc * 64 + nt * 16 + lr;
        float bv = bias[n];
        int which = n >> 10;
        int h = (n >> 6) & 15;
        int dd = n & 63;
#pragma unroll
        for (int mt = 0; mt < 4; ++mt) {
            int m0 = bm * 128 + wr * 64 + mt * 16 + g * 4;
            int bb = m0 >> 11, s0 = m0 & 2047;
            if (which == 2) {
                s16x4 o;
#pragma unroll
                for (int r = 0; r < 4; ++r) o[r] = f2bf(acc[mt][nt][r] + bv);
                *reinterpret_cast<s16x4*>(
                    Vto + ((size_t)(bb * 16 + h) * 64 + dd) * 2048 + s0) = o;
            } else {
                short* base = (which == 0) ? Qo : Ko;
#pragma unroll
                for (int r = 0; r < 4; ++r)
                    base[(((size_t)bb * 16 + h) * 2048 + s0 + r) * 64 + dd] =
                        f2bf(acc[mt][nt][r] + bv);
            }
        }
    }
}

// ---------------- attn ----------------
// grid 512; id = (bh&7) + 8*(qt + 16*(bh>>3)) -> XCD(id%8)==bh%8.
// 512 threads = 8 waves x 16 q-rows, KVBLK=64, 4-deep K/V ring, 2-deep bias.
__global__ __launch_bounds__(512, 4) void attn_kernel(
    const short* __restrict__ Qw, const short* __restrict__ Kw, const short* __restrict__ Vtw,
    const float* __restrict__ attnB, float* __restrict__ out)
{
    __shared__ short Ks [4][64 * 64];   // 32 KB ring
    __shared__ short Vts[4][64 * 64];   // 32 KB ring
    __shared__ short Ps [8][16 * 64];   // 16 KB

    int id = blockIdx.x;
    int bh3 = id & 7;
    int qt  = (id >> 3) & 15;
    int bh  = ((id >> 7) << 3) | bh3;
    int b = bh >> 4, h = bh & 15;
    int tid = threadIdx.x;
    int wave = tid >> 6, lane = tid & 63, g = lane >> 4, lr = lane & 15;

    const short* Qb = Qw  + (size_t)bh * 2048 * 64;
    const short* Kb = Kw  + (size_t)bh * 2048 * 64;
    const short* Vb = Vtw + (size_t)bh * 64 * 2048;
    const float* Bp = attnB + (size_t)bh * 2048 * 2048;

    int qbase = qt * 128 + wave * 16;

    bf16x8 qf0, qf1;
    {
        const short* qp = Qb + (size_t)(qbase + lr) * 64 + g * 8;
        qf0 = *reinterpret_cast<const bf16x8*>(qp);
        qf1 = *reinterpret_cast<const bf16x8*>(qp + 32);
    }
    const float* brow = Bp + (size_t)(qbase + lr) * 2048 + g * 8;

    f32x4 Os[4], Ob[4];
#pragma unroll
    for (int dt = 0; dt < 4; ++dt) { Os[dt] = (f32x4){0.f,0.f,0.f,0.f}; Ob[dt] = (f32x4){0.f,0.f,0.f,0.f}; }
    float lsum = 0.f;

#define STAGE_KV(buf, ktt) do {                                                   \
    int row = tid >> 3, cc = tid & 7;                                             \
    int scc = (cc ^ (row & 7)) * 8;                                               \
    gll16(Kb + (size_t)((ktt) * 64 + row) * 64 + scc,                             \
          &Ks[buf][wave * 512]);                                                  \
    gll16(Vb + (size_t)row * 2048 + (ktt) * 64 + scc,                             \
          &Vts[buf][wave * 512]);                                                 \
} while (0)

#define LOADB(d0, d1, d2, d3, ktt) do {                                           \
    const float* bp_ = brow + (size_t)(ktt) * 64;                                 \
    d0 = *reinterpret_cast<const f32x4*>(bp_);                                    \
    d1 = *reinterpret_cast<const f32x4*>(bp_ + 4);                                \
    d2 = *reinterpret_cast<const f32x4*>(bp_ + 32);                               \
    d3 = *reinterpret_cast<const f32x4*>(bp_ + 36);                               \
} while (0)

#define COMPUTE(cur, xb0, xb1) do {                                               \
    f32x4 S[4];                                                                   \
    __builtin_amdgcn_s_setprio(1);                                                \
    _Pragma("unroll")                                                             \
    for (int nt = 0; nt < 4; ++nt) {                                              \
        int row = nt * 16 + lr;                                                   \
        bf16x8 kf0 = *reinterpret_cast<const bf16x8*>(&Ks[cur][row * 64 + (((g    ) ^ (lr & 7)) * 8)]); \
        bf16x8 kf1 = *reinterpret_cast<const bf16x8*>(&Ks[cur][row * 64 + (((g + 4) ^ (lr & 7)) * 8)]); \
        f32x4 s = (f32x4){0.f,0.f,0.f,0.f};                                       \
        s = __builtin_amdgcn_mfma_f32_16x16x32_bf16(kf0, qf0, s, 0, 0, 0);        \
        s = __builtin_amdgcn_mfma_f32_16x16x32_bf16(kf1, qf1, s, 0, 0, 0);        \
        S[nt] = s;                                                                \
    }                                                                             \
    __builtin_amdgcn_s_setprio(0);                                                \
    _Pragma("unroll")                                                             \
    for (int nt = 0; nt < 4; ++nt)                                                \
        _Pragma("unroll")                                                         \
        for (int r = 0; r < 4; ++r) {                                             \
            float p = exp2f(S[nt][r] * 0.1803368801111f);                         \
            S[nt][r] = p;                                                         \
            lsum += p;                                                            \
        }                                                                         \
    short* psw = &Ps[wave][lr * 64];                                              \
    _Pragma("unroll")                                                             \
    for (int nt = 0; nt < 4; ++nt)                                                \
        _Pragma("unroll")                                                         \
        for (int rp = 0; rp < 2; ++rp) {                                          \
            unsigned w = cvt_pk_bf16(S[nt][2 * rp], S[nt][2 * rp + 1]);           \
            int kp = 8 * nt + 2 * g + rp;                                         \
            int bi = kp >> 2, off = kp & 3;                                       \
            *reinterpret_cast<unsigned*>(psw + ((bi ^ (lr & 7)) << 3) + off * 2) = w; \
        }                                                                         \
    bf16x8 pf0 = *reinterpret_cast<const bf16x8*>(&Ps[wave][lr * 64 + (((g    ) ^ (lr & 7)) * 8)]); \
    bf16x8 pf1 = *reinterpret_cast<const bf16x8*>(&Ps[wave][lr * 64 + (((g + 4) ^ (lr & 7)) * 8)]); \
    __builtin_amdgcn_s_setprio(1);                                                \
    _Pragma("unroll")                                                             \
    for (int dt = 0; dt < 4; ++dt) {                                              \
        int row = dt * 16 + lr;                                                   \
        bf16x8 v0 = *reinterpret_cast<const bf16x8*>(&Vts[cur][row * 64 + (((g    ) ^ (lr & 7)) * 8)]); \
        bf16x8 v1 = *reinterpret_cast<const bf16x8*>(&Vts[cur][row * 64 + (((g + 4) ^ (lr & 7)) * 8)]); \
        Os[dt] = __builtin_amdgcn_mfma_f32_16x16x32_bf16(pf0, v0, Os[dt], 0, 0, 0); \
        Os[dt] = __builtin_amdgcn_mfma_f32_16x16x32_bf16(pf1, v1, Os[dt], 0, 0, 0); \
        Ob[dt] = __builtin_amdgcn_mfma_f32_16x16x32_bf16(xb0, v0, Ob[dt], 0, 0, 0); \
        Ob[dt] = __builtin_amdgcn_mfma_f32_16x16x32_bf16(xb1, v1, Ob[dt], 0, 0, 0); \
    }                                                                             \
    __builtin_amdgcn_s_setprio(0);                                                \
} while (0)

    f32x4 a0, a1, a2, a3, p0, p1, p2, p3;

    // prologue FIFO: S0, B0, B1, S1, S2  -> need S0,B0 -> vmcnt(8)
    STAGE_KV(0, 0);
    __builtin_amdgcn_sched_barrier(0);
    LOADB(a0, a1, a2, a3, 0);
    LOADB(p0, p1, p2, p3, 1);
    __builtin_amdgcn_sched_barrier(0);
    STAGE_KV(1, 1);
    STAGE_KV(2, 2);
    __builtin_amdgcn_sched_barrier(0);
    asm volatile("s_waitcnt vmcnt(8)" ::: "memory");
    __builtin_amdgcn_s_barrier();
    __builtin_amdgcn_sched_barrier(0);

    for (int t = 0; t < 8; ++t) {
        // ---- j=0: kt=4t, ring buf 0, bias set A ----
        {
            int kt = 4 * t;
            bf16x8 bbf0 = pack8(a0, a1);
            bf16x8 bbf1 = pack8(a2, a3);
            if (kt <= 28) STAGE_KV(3, kt + 3);          // (kt+3)&3 == 3
            __builtin_amdgcn_sched_barrier(0);
            if (kt <= 29) LOADB(a0, a1, a2, a3, kt + 2);
            __builtin_amdgcn_sched_barrier(0);
            COMPUTE(0, bbf0, bbf1);
            asm volatile("s_waitcnt vmcnt(6)" ::: "memory");   // kt max 28: steady count valid
            __builtin_amdgcn_s_barrier();
            __builtin_amdgcn_sched_barrier(0);
        }
        // ---- j=1: kt=4t+1, buf 1, bias set P ----
        {
            int kt = 4 * t + 1;
            bf16x8 bbf0 = pack8(p0, p1);
            bf16x8 bbf1 = pack8(p2, p3);
            if (kt <= 28) STAGE_KV(0, kt + 3);
            __builtin_amdgcn_sched_barrier(0);
            if (kt <= 29) LOADB(p0, p1, p2, p3, kt + 2);
            __builtin_amdgcn_sched_barrier(0);
            COMPUTE(1, bbf0, bbf1);
            if (t < 7) { asm volatile("s_waitcnt vmcnt(6)" ::: "memory"); }
            else       { asm volatile("s_waitcnt vmcnt(4)" ::: "memory"); }  // kt=29
            __builtin_amdgcn_s_barrier();
            __builtin_amdgcn_sched_barrier(0);
        }
        // ---- j=2: kt=4t+2, buf 2, bias set A ----
        {
            int kt = 4 * t + 2;
            bf16x8 bbf0 = pack8(a0, a1);
            bf16x8 bbf1 = pack8(a2, a3);
            if (kt <= 28) STAGE_KV(1, kt + 3);
            __builtin_amdgcn_sched_barrier(0);
            if (kt <= 29) LOADB(a0, a1, a2, a3, kt + 2);
            __builtin_amdgcn_sched_barrier(0);
            COMPUTE(2, bbf0, bbf1);
            if (t < 7) { asm volatile("s_waitcnt vmcnt(6)" ::: "memory"); }
            else       { asm volatile("s_waitcnt vmcnt(0)" ::: "memory"); }  // kt=30
            __builtin_amdgcn_s_barrier();
            __builtin_amdgcn_sched_barrier(0);
        }
        // ---- j=3: kt=4t+3, buf 3, bias set P ----
        {
            int kt = 4 * t + 3;
            bf16x8 bbf0 = pack8(p0, p1);
            bf16x8 bbf1 = pack8(p2, p3);
            if (kt <= 28) STAGE_KV(2, kt + 3);
            __builtin_amdgcn_sched_barrier(0);
            if (kt <= 29) LOADB(p0, p1, p2, p3, kt + 2);
            __builtin_amdgcn_sched_barrier(0);
            COMPUTE(3, bbf0, bbf1);
            if (t < 7) {
                asm volatile("s_waitcnt vmcnt(6)" ::: "memory");
                __builtin_amdgcn_s_barrier();
                __builtin_amdgcn_sched_barrier(0);
            }
            // t==7 (kt=31): last iter, no trailing wait/barrier
        }
    }
#undef STAGE_KV
#undef LOADB
#undef COMPUTE

    float l = lsum;
    l += __shfl_xor(l, 16);
    l += __shfl_xor(l, 32);
    float inv = 1.0f / l;
#pragma unroll
    for (int r = 0; r < 4; ++r) {
        float invr = __shfl(inv, g * 4 + r);
        int q = qbase + g * 4 + r;
#pragma unroll
        for (int dt = 0; dt < 4; ++dt) {
            int dcol = dt * 16 + lr;
            float v = Os[dt][r] * invr + Ob[dt][r];
            __builtin_nontemporal_store(v, &out[((size_t)(b * 2048 + q) * 16 + h) * 64 + dcol]);
        }
    }
}

extern "C" void kernel_launch(void* const* d_in, const int* in_sizes, int n_in,
                              void* d_out, int out_size, void* d_ws, size_t ws_size,
                              hipStream_t stream) {
    const float* x     = (const float*)d_in[0];
    const float* attnB = (const float*)d_in[1];
    const float* W     = (const float*)d_in[2];
    const float* bias  = (const float*)d_in[3];
    float* out = (float*)d_out;

    short* ws = (short*)d_ws;
    short* xb = ws;                // 4,194,304 shorts
    short* Wt = xb + 4194304;      // 3,145,728
    short* Q  = Wt + 3145728;      // 4,194,304
    short* K  = Q  + 4194304;      // 4,194,304
    short* Vt = K  + 4194304;      // 4,194,304

    conv_x_kernel<<<4096, 256, 0, stream>>>(x, xb);
    wtrans_kernel<<<dim3(16, 48), 256, 0, stream>>>(W, Wt);
    qkv_gemm_kernel<<<dim3(32, 24), 256, 0, stream>>>(xb, Wt, bias, Q, K, Vt);
    attn_kernel<<<512, 512, 0, stream>>>(Q, K, Vt, attnB, out);
}